// Round 1
// baseline (71836.261 us; speedup 1.0000x reference)
//
#include <hip/hip_runtime.h>
#include <math.h>

static constexpr int HID_C = 1024;   // hidden size
static constexpr int NBLK  = 256;    // one block per CU; each owns 4 hidden units
static constexpr int NTHR  = 256;    // 4 waves
static constexpr int PCOLS = 96;     // K_MIX * 3 * IN_DIM

__device__ __forceinline__ float sigmoid_f(float x) { return 1.0f / (1.0f + __expf(-x)); }

__global__ __launch_bounds__(NTHR)
void gru_fused(const float* __restrict__ ex,   // [T,8]
               const float* __restrict__ Wx,   // [8,3072]
               const float* __restrict__ Wh,   // [1024,3072]
               const float* __restrict__ bx,   // [3072]
               const float* __restrict__ bh,   // [3072]
               const float* __restrict__ Wd,   // [1024,96]
               const float* __restrict__ bd,   // [96]
               float* __restrict__ out,        // [T,96]
               float* __restrict__ hbuf,       // [2,1024] in ws (zeroed)
               int*   __restrict__ flags,      // [256] in ws (zeroed)
               int T)
{
  const int b   = blockIdx.x;
  const int tid = threadIdx.x;
  const int w   = tid >> 6;       // wave 0..3
  const int l   = tid & 63;       // lane
  const int hu  = (b << 2) + w;   // hidden unit owned by this wave

  __shared__ float h_s[HID_C];
  __shared__ float x_s[8];

  // ---- preload Wh slice into registers: whr[g][k] = Wh[l+64k][g*1024+hu]
  float whr[3][16];
#pragma unroll
  for (int g = 0; g < 3; ++g) {
#pragma unroll
    for (int k = 0; k < 16; ++k)
      whr[g][k] = Wh[(size_t)(l + (k << 6)) * 3072 + g * 1024 + hu];
  }
  float wxr[3][8], bxr[3], bhr[3];
#pragma unroll
  for (int g = 0; g < 3; ++g) {
    bxr[g] = bx[g * 1024 + hu];
    bhr[g] = bh[g * 1024 + hu];
#pragma unroll
    for (int i = 0; i < 8; ++i) wxr[g][i] = Wx[i * 3072 + g * 1024 + hu];
  }
  // wave 3 of blocks 0..95 also owns one output-projection column
  const bool pw = (w == 3) && (b < PCOLS);
  float wdr[16];
  float bdv = 0.f;
  if (pw) {
#pragma unroll
    for (int k = 0; k < 16; ++k) wdr[k] = Wd[(size_t)(l + (k << 6)) * PCOLS + b];
    bdv = bd[b];
  } else {
#pragma unroll
    for (int k = 0; k < 16; ++k) wdr[k] = 0.f;
  }

  for (int s = 0; s <= T; ++s) {
    // stage teacher-forced input x_in[s] = (s==0) ? 0 : ex[s-1]
    if (tid < 8) x_s[tid] = (s >= 1) ? ex[(size_t)(s - 1) * 8 + tid] : 0.f;

    // distributed barrier: wait until every block published step s
    if (s > 0) {
      while (__hip_atomic_load(&flags[tid], __ATOMIC_RELAXED, __HIP_MEMORY_SCOPE_AGENT) < s)
        __builtin_amdgcn_s_sleep(1);
    }
    __syncthreads();

    // stage h_s (coherent loads from LLC; L1/XCD-L2 may be stale)
    {
      const float* hb = hbuf + ((s & 1) ? HID_C : 0);
#pragma unroll
      for (int j = 0; j < 4; ++j) {
        int idx = tid + (j << 8);
        h_s[idx] = __hip_atomic_load(&hb[idx], __ATOMIC_RELAXED, __HIP_MEMORY_SCOPE_AGENT);
      }
    }
    __syncthreads();

    if (s < T) {
      float hreg[16];
#pragma unroll
      for (int k = 0; k < 16; ++k) hreg[k] = h_s[l + (k << 6)];

      float a0 = 0.f, a1 = 0.f, a2 = 0.f, ap = 0.f;
#pragma unroll
      for (int k = 0; k < 16; ++k) {
        a0 = fmaf(hreg[k], whr[0][k], a0);
        a1 = fmaf(hreg[k], whr[1][k], a1);
        a2 = fmaf(hreg[k], whr[2][k], a2);
        ap = fmaf(hreg[k], wdr[k], ap);
      }
#pragma unroll
      for (int off = 32; off; off >>= 1) {
        a0 += __shfl_xor(a0, off, 64);
        a1 += __shfl_xor(a1, off, 64);
        a2 += __shfl_xor(a2, off, 64);
        ap += __shfl_xor(ap, off, 64);
      }

      if (l == 0) {
        // gx = x_in @ Wx + bx  (8-wide, trivial)
        float gz = bxr[0], gr = bxr[1], gc = bxr[2];
#pragma unroll
        for (int i = 0; i < 8; ++i) {
          float xi = x_s[i];
          gz = fmaf(xi, wxr[0][i], gz);
          gr = fmaf(xi, wxr[1][i], gr);
          gc = fmaf(xi, wxr[2][i], gc);
        }
        // Keras GRU reset_after=True, gate order (z, r, h)
        float z    = sigmoid_f(gz + a0 + bhr[0]);
        float r    = sigmoid_f(gr + a1 + bhr[1]);
        float cand = tanhf(gc + r * (a2 + bhr[2]));
        float hnew = z * h_s[hu] + (1.f - z) * cand;
        float* hn = hbuf + (((s + 1) & 1) ? HID_C : 0);
        __hip_atomic_store(&hn[hu], hnew, __ATOMIC_RELAXED, __HIP_MEMORY_SCOPE_AGENT);
        // fused output projection: p[s-1][b] from h_s (= hs[s-1])
        if (pw && s >= 1) out[(size_t)(s - 1) * PCOLS + b] = ap + bdv;
      }
      __syncthreads();  // drains vmcnt(0): all stores of this block complete
      if (tid == 0)
        __hip_atomic_store(&flags[b], s + 1, __ATOMIC_RELEASE, __HIP_MEMORY_SCOPE_AGENT);
    } else {
      // epilogue: p[T-1] from final h
      if (pw) {
        float ap = 0.f;
#pragma unroll
        for (int k = 0; k < 16; ++k) ap = fmaf(h_s[l + (k << 6)], wdr[k], ap);
#pragma unroll
        for (int off = 32; off; off >>= 1) ap += __shfl_xor(ap, off, 64);
        if (l == 0) out[(size_t)(T - 1) * PCOLS + b] = ap + bdv;
      }
    }
  }
}

extern "C" void kernel_launch(void* const* d_in, const int* in_sizes, int n_in,
                              void* d_out, int out_size, void* d_ws, size_t ws_size,
                              hipStream_t stream)
{
  const float* ex = (const float*)d_in[0];
  const float* Wx = (const float*)d_in[1];
  const float* Wh = (const float*)d_in[2];
  const float* bx = (const float*)d_in[3];
  const float* bh = (const float*)d_in[4];
  const float* Wd = (const float*)d_in[5];
  const float* bd = (const float*)d_in[6];
  float* out  = (float*)d_out;
  float* hbuf = (float*)d_ws;
  int*   flags = (int*)d_ws + 2 * HID_C;
  const int T = in_sizes[0] / 8;

  // zero h0 (both buffers) + flags — graph-capture safe
  hipMemsetAsync(d_ws, 0, (2 * HID_C + NBLK) * sizeof(float), stream);
  hipLaunchKernelGGL(gru_fused, dim3(NBLK), dim3(NTHR), 0, stream,
                     ex, Wx, Wh, bx, bh, Wd, bd, out, hbuf, flags, T);
}

// Round 2
// 28699.426 us; speedup vs baseline: 2.5031x; 2.5031x over previous
//
#include <hip/hip_runtime.h>
#include <math.h>

static constexpr int HID   = 1024;  // hidden size
static constexpr int NGRP  = 16;    // independent chunk groups
static constexpr int GPB   = 16;    // blocks per group (each owns 64 hidden units)
static constexpr int WARM  = 96;    // warmup steps re-deriving state (contraction ~0.6/step)
static constexpr int NTHR  = 1024;  // 16 waves
static constexpr int PCOLS = 96;    // K_MIX*3*IN_DIM

__device__ __forceinline__ float sigmoid_f(float x) { return 1.0f / (1.0f + __expf(-x)); }

__global__ __launch_bounds__(NTHR)
void gru_chunked(const float* __restrict__ ex,   // [T,8]
                 const float* __restrict__ Wx,   // [8,3072]
                 const float* __restrict__ Wh,   // [1024,3072]
                 const float* __restrict__ bx,   // [3072]
                 const float* __restrict__ bh,   // [3072]
                 const float* __restrict__ Wd,   // [1024,96]
                 const float* __restrict__ bd,   // [96]
                 float* __restrict__ out,        // [T,96]
                 unsigned long long* __restrict__ pkt, // [NGRP][2][HID] tagged packets (zeroed)
                 int T)
{
  const int g   = blockIdx.x >> 4;   // group / chunk
  const int p   = blockIdx.x & 15;   // block within group
  const int tid = threadIdx.x;
  const int w   = tid >> 6;          // wave 0..15
  const int l   = tid & 63;          // lane

  unsigned long long* gpk = pkt + (size_t)g * (2 * HID);

  const int LCH         = T >> 4;                  // 512 for T=8192
  const int chunk_begin = g * LCH;
  const int s0          = (g == 0) ? 0 : (chunk_begin - WARM);
  const int n_local     = (chunk_begin + LCH) - s0;

  __shared__ float h_s[HID];
  __shared__ float x_s[8];

  // ---- weights in registers: wave w owns units U = 64p + 4w + uu (uu=0..3)
  const int ubase = 64 * p + 4 * w;
  float whz[4][16], whrr[4][16], whc[4][16];
#pragma unroll
  for (int uu = 0; uu < 4; ++uu) {
    const int cz = 0 * HID + ubase + uu;
    const int cr = 1 * HID + ubase + uu;
    const int cc = 2 * HID + ubase + uu;
#pragma unroll
    for (int k = 0; k < 16; ++k) {
      const size_t row = (size_t)(l + (k << 6)) * 3072;
      whz[uu][k]  = Wh[row + cz];
      whrr[uu][k] = Wh[row + cr];
      whc[uu][k]  = Wh[row + cc];
    }
  }
  // per-lane finalize constants for unit myu = ubase + (l&3) (used by lanes 0..3)
  const int myu = ubase + (l & 3);
  float wxz[8], wxr[8], wxc[8];
#pragma unroll
  for (int i = 0; i < 8; ++i) {
    wxz[i] = Wx[i * 3072 + 0 * HID + myu];
    wxr[i] = Wx[i * 3072 + 1 * HID + myu];
    wxc[i] = Wx[i * 3072 + 2 * HID + myu];
  }
  const float bxz = bx[0 * HID + myu], bxrv = bx[1 * HID + myu], bxc = bx[2 * HID + myu];
  const float bhz = bh[0 * HID + myu], bhrv = bh[1 * HID + myu], bhc = bh[2 * HID + myu];

  // output projection: waves 0..5 own column pcol = 6p + w
  const bool pw = (w < 6);
  const int  pcol = 6 * p + w;
  float wd[16];
  float bdv = 0.f;
  if (pw) {
#pragma unroll
    for (int k = 0; k < 16; ++k) wd[k] = Wd[(size_t)(l + (k << 6)) * PCOLS + pcol];
    bdv = bd[pcol];
  } else {
#pragma unroll
    for (int k = 0; k < 16; ++k) wd[k] = 0.f;
  }

  for (int j = 0; j <= n_local; ++j) {
    const int t = s0 + j;  // global step consumed this iteration

    // stage teacher-forced input x_in[t] = (t==0) ? 0 : ex[t-1]
    if (j < n_local && tid < 8)
      x_s[tid] = (t >= 1) ? ex[(size_t)(t - 1) * 8 + tid] : 0.f;

    // poll tagged packet (tag j) and stage h into LDS — data IS the flag
    {
      unsigned long long* slot = gpk + (size_t)((j & 1) * HID + tid);
      unsigned long long v = __hip_atomic_load(slot, __ATOMIC_RELAXED, __HIP_MEMORY_SCOPE_AGENT);
      while ((unsigned int)(v >> 32) != (unsigned int)j) {
        __builtin_amdgcn_s_sleep(1);
        v = __hip_atomic_load(slot, __ATOMIC_RELAXED, __HIP_MEMORY_SCOPE_AGENT);
      }
      union { unsigned int u; float f; } cv;
      cv.u = (unsigned int)v;
      h_s[tid] = cv.f;
    }
    __syncthreads();

    // fused output row t-1 (staged h = hs[t-1])
    const int tp = t - 1;
    if (pw && tp >= chunk_begin) {
      float ap = 0.f;
#pragma unroll
      for (int k = 0; k < 16; ++k) ap = fmaf(h_s[l + (k << 6)], wd[k], ap);
#pragma unroll
      for (int m = 32; m; m >>= 1) ap += __shfl_xor(ap, m, 64);
      if (l == 0) out[(size_t)tp * PCOLS + pcol] = ap + bdv;
    }

    if (j < n_local) {
      float hr[16];
#pragma unroll
      for (int k = 0; k < 16; ++k) hr[k] = h_s[l + (k << 6)];

      float az[4] = {0, 0, 0, 0}, ar[4] = {0, 0, 0, 0}, ac[4] = {0, 0, 0, 0};
#pragma unroll
      for (int k = 0; k < 16; ++k) {
#pragma unroll
        for (int uu = 0; uu < 4; ++uu) {
          az[uu] = fmaf(hr[k], whz[uu][k],  az[uu]);
          ar[uu] = fmaf(hr[k], whrr[uu][k], ar[uu]);
          ac[uu] = fmaf(hr[k], whc[uu][k],  ac[uu]);
        }
      }
#pragma unroll
      for (int uu = 0; uu < 4; ++uu) {
#pragma unroll
        for (int m = 32; m; m >>= 1) {
          az[uu] += __shfl_xor(az[uu], m, 64);
          ar[uu] += __shfl_xor(ar[uu], m, 64);
          ac[uu] += __shfl_xor(ac[uu], m, 64);
        }
      }

      if (l < 4) {
        // static selection (no runtime-indexed array -> stays in registers)
        const int q = l & 3;
        const float sz = (q == 0) ? az[0] : (q == 1) ? az[1] : (q == 2) ? az[2] : az[3];
        const float sr = (q == 0) ? ar[0] : (q == 1) ? ar[1] : (q == 2) ? ar[2] : ar[3];
        const float sc = (q == 0) ? ac[0] : (q == 1) ? ac[1] : (q == 2) ? ac[2] : ac[3];

        float gz = bxz, gr = bxrv, gc = bxc;
#pragma unroll
        for (int i = 0; i < 8; ++i) {
          const float xi = x_s[i];
          gz = fmaf(xi, wxz[i], gz);
          gr = fmaf(xi, wxr[i], gr);
          gc = fmaf(xi, wxc[i], gc);
        }
        // Keras GRU reset_after=True, gate order (z, r, h)
        const float z    = sigmoid_f(gz + sz + bhz);
        const float r    = sigmoid_f(gr + sr + bhrv);
        const float cand = tanhf(gc + r * (sc + bhc));
        const float hnew = z * h_s[myu] + (1.f - z) * cand;

        union { float f; unsigned int u; } cv;
        cv.f = hnew;
        const unsigned long long pv =
            ((unsigned long long)(unsigned int)(j + 1) << 32) | (unsigned long long)cv.u;
        __hip_atomic_store(gpk + (size_t)(((j + 1) & 1) * HID + myu), pv,
                           __ATOMIC_RELAXED, __HIP_MEMORY_SCOPE_AGENT);
      }
    }
    __syncthreads();  // protect h_s/x_s against next-iteration overwrite
  }
}

extern "C" void kernel_launch(void* const* d_in, const int* in_sizes, int n_in,
                              void* d_out, int out_size, void* d_ws, size_t ws_size,
                              hipStream_t stream)
{
  const float* ex = (const float*)d_in[0];
  const float* Wx = (const float*)d_in[1];
  const float* Wh = (const float*)d_in[2];
  const float* bx = (const float*)d_in[3];
  const float* bh = (const float*)d_in[4];
  const float* Wd = (const float*)d_in[5];
  const float* bd = (const float*)d_in[6];
  float* out = (float*)d_out;
  unsigned long long* pkt = (unsigned long long*)d_ws;
  const int T = in_sizes[0] / 8;

  // zero packets: tag 0 + h 0 == valid initial state for every group
  hipMemsetAsync(d_ws, 0, (size_t)NGRP * 2 * HID * sizeof(unsigned long long), stream);
  hipLaunchKernelGGL(gru_chunked, dim3(NGRP * GPB), dim3(NTHR), 0, stream,
                     ex, Wx, Wh, bx, bh, Wd, bd, out, pkt, T);
}

// Round 4
// 3818.854 us; speedup vs baseline: 18.8109x; 7.5152x over previous
//
#include <hip/hip_runtime.h>
#include <math.h>

static constexpr int HID   = 1024;  // hidden size
static constexpr int NGRP  = 8;     // independent chunk groups (VGPR capacity bound: 8 fp32 Wh replicas max)
static constexpr int GPB   = 32;    // blocks per group; block owns 32 hidden units
static constexpr int WARM  = 96;    // warmup steps re-deriving state from h=0 (contraction ~0.6/step)
static constexpr int NTHR  = 256;   // 4 waves; 1 wave/SIMD -> VGPR cap 512
static constexpr int PCOLS = 96;    // K_MIX*3*IN_DIM

__device__ __forceinline__ float sigmoid_f(float x) { return 1.0f / (1.0f + __expf(-x)); }

// Reduce 8 accumulators across 64 lanes: returns full-lane sum of a[l&7] in every lane.
// Stages 1,2,4 fold accumulators while partitioning lanes; stages 8,16,32 finish the lane sum.
__device__ __forceinline__ float reduce8(const float a[8], int l) {
  const bool m1 = l & 1, m2 = l & 2, m4 = l & 4;
  float b0 = (m1 ? a[1] : a[0]) + __shfl_xor((m1 ? a[0] : a[1]), 1, 64);
  float b1 = (m1 ? a[3] : a[2]) + __shfl_xor((m1 ? a[2] : a[3]), 1, 64);
  float b2 = (m1 ? a[5] : a[4]) + __shfl_xor((m1 ? a[4] : a[5]), 1, 64);
  float b3 = (m1 ? a[7] : a[6]) + __shfl_xor((m1 ? a[6] : a[7]), 1, 64);
  float c0 = (m2 ? b1 : b0) + __shfl_xor((m2 ? b0 : b1), 2, 64);
  float c1 = (m2 ? b3 : b2) + __shfl_xor((m2 ? b2 : b3), 2, 64);
  float d  = (m4 ? c1 : c0) + __shfl_xor((m4 ? c0 : c1), 4, 64);
  d += __shfl_xor(d, 8, 64);
  d += __shfl_xor(d, 16, 64);
  d += __shfl_xor(d, 32, 64);
  return d;
}

__global__ __launch_bounds__(NTHR, 1)
void gru_chunked8(const float* __restrict__ ex,   // [T,8]
                  const float* __restrict__ Wx,   // [8,3072]
                  const float* __restrict__ Wh,   // [1024,3072]
                  const float* __restrict__ bx,   // [3072]
                  const float* __restrict__ bh,   // [3072]
                  const float* __restrict__ Wd,   // [1024,96]
                  const float* __restrict__ bd,   // [96]
                  float* __restrict__ out,        // [T,96]
                  unsigned long long* __restrict__ pkt, // [NGRP][2][HID] tagged packets (zeroed)
                  int T)
{
  const int g   = blockIdx.x & 7;    // group (round-robin across XCDs)
  const int p   = blockIdx.x >> 3;   // block within group, 0..31
  const int tid = threadIdx.x;
  const int w   = tid >> 6;          // wave 0..3
  const int l   = tid & 63;          // lane

  unsigned long long* gpk = pkt + (size_t)g * (2 * HID);

  const int LCH         = T >> 3;                  // 1024 for T=8192
  const int chunk_begin = g * LCH;
  const int chunk_end   = chunk_begin + LCH;
  const int s0          = (g == 0) ? 0 : (chunk_begin - WARM);
  const int n_local     = chunk_end - s0;

  __shared__ float h_s[HID];
  __shared__ float x_s[8];
  __shared__ float wd_s[3 * HID];   // 3 output-projection columns per block
  __shared__ float wx_s[3 * 32 * 8]; // Wx slice for this block's 32 units: [gate][unit_local][i]

  // ---- Wh slice in registers: wave w owns units ubase..ubase+7 (384 VGPR/lane)
  const int ubase = 32 * p + 8 * w;
  float whz[8][16], whr_[8][16], whc[8][16];
#pragma unroll
  for (int uu = 0; uu < 8; ++uu) {
    const int cz = 0 * HID + ubase + uu;
    const int cr = 1 * HID + ubase + uu;
    const int cc = 2 * HID + ubase + uu;
#pragma unroll
    for (int k = 0; k < 16; ++k) {
      const size_t row = (size_t)(l + (k << 6)) * 3072;
      whz[uu][k]  = Wh[row + cz];
      whr_[uu][k] = Wh[row + cr];
      whc[uu][k]  = Wh[row + cc];
    }
  }
  // finalize constants for unit myu = ubase + (l&7) (used by lanes 0..7)
  const int myu = ubase + (l & 7);
  const float bxz = bx[0 * HID + myu], bxrv = bx[1 * HID + myu], bxc = bx[2 * HID + myu];
  const float bhz = bh[0 * HID + myu], bhrv = bh[1 * HID + myu], bhc = bh[2 * HID + myu];

  // Wx slice -> LDS: wx_s[gt*256 + u*8 + i] = Wx[i*3072 + gt*1024 + 32p + u]
  for (int idx = tid; idx < 3 * 32 * 8; idx += NTHR) {
    const int gt = idx >> 8, rem = idx & 255, u = rem >> 3, i = rem & 7;
    wx_s[idx] = Wx[(size_t)i * 3072 + gt * HID + 32 * p + u];
  }
  // out-projection: waves 0..2 own column pcol = 3p + w; weights staged in LDS
  const bool pw   = (w < 3);
  const int  pcol = 3 * p + w;
  const float bdv = pw ? bd[pcol] : 0.f;
#pragma unroll
  for (int c = 0; c < 3; ++c)
    for (int idx = tid; idx < HID; idx += NTHR)
      wd_s[c * HID + idx] = Wd[(size_t)idx * PCOLS + (3 * p + c)];
  __syncthreads();

  const int mylocal = 8 * w + (l & 7);  // local unit index 0..31 (lanes 0..7)

  for (int j = 0; j <= n_local; ++j) {
    const int t = s0 + j;  // global step consumed this iteration

    // teacher-forced input x_in[t] = (t==0) ? 0 : ex[t-1]  (issued before poll, overlaps)
    if (j < n_local && tid < 8)
      x_s[tid] = (t >= 1) ? ex[(size_t)(t - 1) * 8 + tid] : 0.f;

    // poll tagged packets (tag j): data IS the flag; issue all 4 loads, then verify
    {
      unsigned long long* base = gpk + (size_t)(j & 1) * HID;
      unsigned long long v[4];
#pragma unroll
      for (int q = 0; q < 4; ++q)
        v[q] = __hip_atomic_load(base + tid + (q << 8), __ATOMIC_RELAXED, __HIP_MEMORY_SCOPE_AGENT);
#pragma unroll
      for (int q = 0; q < 4; ++q) {
        while ((unsigned int)(v[q] >> 32) != (unsigned int)j) {
          __builtin_amdgcn_s_sleep(1);
          v[q] = __hip_atomic_load(base + tid + (q << 8), __ATOMIC_RELAXED, __HIP_MEMORY_SCOPE_AGENT);
        }
        union { unsigned int ui; float f; } cv;
        cv.ui = (unsigned int)v[q];
        h_s[tid + (q << 8)] = cv.f;
      }
    }
    __syncthreads();

    if (j < n_local) {
      float hreg[16];
#pragma unroll
      for (int k = 0; k < 16; ++k) hreg[k] = h_s[l + (k << 6)];

      // gate-sequential dots (8 live accums) + folded butterfly reduce
      float a[8];
      float sz, sr, sc;
#pragma unroll
      for (int uu = 0; uu < 8; ++uu) a[uu] = 0.f;
#pragma unroll
      for (int k = 0; k < 16; ++k)
#pragma unroll
        for (int uu = 0; uu < 8; ++uu) a[uu] = fmaf(hreg[k], whz[uu][k], a[uu]);
      sz = reduce8(a, l);
#pragma unroll
      for (int uu = 0; uu < 8; ++uu) a[uu] = 0.f;
#pragma unroll
      for (int k = 0; k < 16; ++k)
#pragma unroll
        for (int uu = 0; uu < 8; ++uu) a[uu] = fmaf(hreg[k], whr_[uu][k], a[uu]);
      sr = reduce8(a, l);
#pragma unroll
      for (int uu = 0; uu < 8; ++uu) a[uu] = 0.f;
#pragma unroll
      for (int k = 0; k < 16; ++k)
#pragma unroll
        for (int uu = 0; uu < 8; ++uu) a[uu] = fmaf(hreg[k], whc[uu][k], a[uu]);
      sc = reduce8(a, l);

      if (l < 8) {
        float gz = bxz, gr = bxrv, gc = bxc;
#pragma unroll
        for (int i = 0; i < 8; ++i) {
          const float xi = x_s[i];
          gz = fmaf(xi, wx_s[0 * 256 + mylocal * 8 + i], gz);
          gr = fmaf(xi, wx_s[1 * 256 + mylocal * 8 + i], gr);
          gc = fmaf(xi, wx_s[2 * 256 + mylocal * 8 + i], gc);
        }
        // Keras GRU reset_after=True, gate order (z, r, h)
        const float z    = sigmoid_f(gz + sz + bhz);
        const float r    = sigmoid_f(gr + sr + bhrv);
        const float cand = tanhf(gc + r * (sc + bhc));
        const float hnew = z * h_s[myu] + (1.f - z) * cand;

        union { float f; unsigned int ui; } cv;
        cv.f = hnew;
        const unsigned long long pv =
            ((unsigned long long)(unsigned int)(j + 1) << 32) | (unsigned long long)cv.ui;
        __hip_atomic_store(gpk + (size_t)(((j + 1) & 1) * HID + myu), pv,
                           __ATOMIC_RELAXED, __HIP_MEMORY_SCOPE_AGENT);
      }
    }

    // fused output row t-1 (staged h = hs[t-1]); off the inter-step critical path
    const int tp = t - 1;
    if (pw && tp >= chunk_begin) {
      float ap = 0.f;
#pragma unroll
      for (int k = 0; k < 16; ++k) ap = fmaf(h_s[l + (k << 6)], wd_s[w * HID + l + (k << 6)], ap);
#pragma unroll
      for (int m = 32; m; m >>= 1) ap += __shfl_xor(ap, m, 64);
      if (l == 0) out[(size_t)tp * PCOLS + pcol] = ap + bdv;
    }

    __syncthreads();  // protect h_s/x_s against next-iteration overwrite
  }
}

extern "C" void kernel_launch(void* const* d_in, const int* in_sizes, int n_in,
                              void* d_out, int out_size, void* d_ws, size_t ws_size,
                              hipStream_t stream)
{
  const float* ex = (const float*)d_in[0];
  const float* Wx = (const float*)d_in[1];
  const float* Wh = (const float*)d_in[2];
  const float* bx = (const float*)d_in[3];
  const float* bh = (const float*)d_in[4];
  const float* Wd = (const float*)d_in[5];
  const float* bd = (const float*)d_in[6];
  float* out = (float*)d_out;
  unsigned long long* pkt = (unsigned long long*)d_ws;
  const int T = in_sizes[0] / 8;

  // zero packets: tag 0 + h 0 == valid initial state for every group
  hipMemsetAsync(d_ws, 0, (size_t)NGRP * 2 * HID * sizeof(unsigned long long), stream);
  hipLaunchKernelGGL(gru_chunked8, dim3(NGRP * GPB), dim3(NTHR), 0, stream,
                     ex, Wx, Wh, bx, bh, Wd, bd, out, pkt, T);
}